// Round 5
// baseline (388.189 us; speedup 1.0000x reference)
//
#include <hip/hip_runtime.h>
#include <hip/hip_bf16.h>
#include <cstdint>

typedef __hip_bfloat16 bf16;
typedef __attribute__((ext_vector_type(8))) short bfrag;   // 8 bf16 (4 VGPRs)
typedef __attribute__((ext_vector_type(4))) float facc;    // 4 fp32 acc

#define B_    16384
#define D_    1024
#define DOUT_ 1024
#define R_    8
#define DH_   512
#define RH_   4096

#define BM 256
#define BN 256
#define BK 64

#define NXCD 8

#define AS1(p) ((const __attribute__((address_space(1))) void*)(p))
#define AS3(p) ((__attribute__((address_space(3))) void*)(p))

// inline-asm ds_read_b128 with explicit placement (post-MFMA read-ahead).
// Discipline per rule 18: consuming MFMA cluster is preceded by
// s_waitcnt lgkmcnt(0) + sched_barrier(0).
#define DSR(dst, addr, off) \
    asm volatile("ds_read_b128 %0, %1 offset:%c2" : "=v"(dst) : "v"(addr), "i"(off))

static __device__ __forceinline__ uint32_t pack2bf(float a, float b) {
    unsigned short ua = __builtin_bit_cast(unsigned short, __float2bfloat16(a));
    unsigned short ub = __builtin_bit_cast(unsigned short, __float2bfloat16(b));
    return (uint32_t)ua | ((uint32_t)ub << 16);
}

// ---------------- fp32 -> bf16 conversion (vectorized) ----------------
__global__ void k_cvt(const float* __restrict__ in, bf16* __restrict__ out, long n)
{
    long i = ((long)blockIdx.x * blockDim.x + threadIdx.x) * 4;
    if (i >= n) return;
    float4 v = *reinterpret_cast<const float4*>(in + i);
    uint2 o;
    o.x = pack2bf(v.x, v.y);
    o.y = pack2bf(v.z, v.w);
    *reinterpret_cast<uint2*>(out + i) = o;
}

// ---- W2 (R,DOUT,DH) -> B4 (DOUT, R*DH) with B4[o][r*DH+h] = W2[r][o][h] ----
__global__ void k_cvt_w2(const float* __restrict__ W2, bf16* __restrict__ out)
{
    int b = blockIdx.x;            // 0 .. R_*DOUT_-1
    int r = b >> 10;               // DOUT_ = 1024
    int o = b & 1023;
    const float4* src = reinterpret_cast<const float4*>(W2 + ((long)r * DOUT_ + o) * DH_);
    bf16* dst = out + (long)o * RH_ + r * DH_;
    int t = threadIdx.x;           // 0..127, covers 512 floats
    float4 v = src[t];
    uint2 p;
    p.x = pack2bf(v.x, v.y);
    p.y = pack2bf(v.z, v.w);
    *reinterpret_cast<uint2*>(dst + t * 4) = p;
}

// ---------------- gate = softmax(x @ Wg.T + bg) ----------------
__global__ __launch_bounds__(256) void k_gate(const float* __restrict__ x,
                                              const float* __restrict__ Wg,
                                              const float* __restrict__ bg,
                                              float* __restrict__ gate)
{
    __shared__ float sWg[R_ * D_];
    __shared__ float sbg[R_];
    for (int i = threadIdx.x; i < R_ * D_ / 4; i += 256)
        reinterpret_cast<float4*>(sWg)[i] = reinterpret_cast<const float4*>(Wg)[i];
    if (threadIdx.x < R_) sbg[threadIdx.x] = bg[threadIdx.x];
    __syncthreads();

    const int lane = threadIdx.x & 63;
    const int wave = threadIdx.x >> 6;
    const int row  = blockIdx.x * 4 + wave;     // grid = B_/4

    const float4* xr = reinterpret_cast<const float4*>(x + (long)row * D_);
    float s[R_] = {};
    #pragma unroll
    for (int c = 0; c < 4; ++c) {
        float4 xv = xr[lane + c * 64];
        #pragma unroll
        for (int r = 0; r < R_; ++r) {
            float4 wv = reinterpret_cast<const float4*>(sWg + r * D_)[lane + c * 64];
            s[r] += xv.x * wv.x + xv.y * wv.y + xv.z * wv.z + xv.w * wv.w;
        }
    }
    #pragma unroll
    for (int r = 0; r < R_; ++r) {
        float v = s[r];
        #pragma unroll
        for (int off = 32; off > 0; off >>= 1) v += __shfl_xor(v, off);
        s[r] = v + sbg[r];
    }
    float m = s[0];
    #pragma unroll
    for (int r = 1; r < R_; ++r) m = fmaxf(m, s[r]);
    float den = 0.f;
    #pragma unroll
    for (int r = 0; r < R_; ++r) { s[r] = __expf(s[r] - m); den += s[r]; }
    float inv = 1.f / den;
    if (lane < R_) gate[(long)row * R_ + lane] = s[lane] * inv;
}

// ======== 256x256 8-phase bf16 MFMA GEMM (read-ahead schedule) ========
// EPI 0: C(bf16) = dot + bias[col]
// EPI 1: C(bf16) = relu(dot + bias[col]) * gate[row][col>>9]
// EPI 2: C(f32)  = dot + sum_r gate[row][r]*b2[r][col]
//
// Quadrants: Q0(Alo,Blo) Q1(Alo,Bhi) Q2(Ahi,Bhi) Q3(Ahi,Blo).
// Fragments for phase p's MFMA are read at the END of phase p-1 (post-MFMA),
// so lgkmcnt(0) never stalls. Staging: 1 half-tile per phase
// (P0:H2(t+1) P1:H3(t+1) P2:H0(t+2) P3:H1(t+2)); vmcnt(4) once per tile at P3.
#define MFMA_BF16 __builtin_amdgcn_mfma_f32_16x16x32_bf16

template <int EPI>
__global__ __launch_bounds__(512, 2)
void k_gemm(const bf16* __restrict__ A, const bf16* __restrict__ Bm,
            const float* __restrict__ bias, const float* __restrict__ gate,
            const float* __restrict__ b2v, void* __restrict__ Cout,
            int M, int N, int K, int gate_row0)
{
    __shared__ char lds[131072];

    const int tid  = threadIdx.x;
    const int lane = tid & 63;
    const int wave = tid >> 6;
    const int wr   = wave >> 2;       // 0..1
    const int wc   = wave & 3;        // 0..3

    // ---- XCD-aware bijective chunked swizzle (m204) ----
    const int nwg  = gridDim.x * gridDim.y;
    const int orig = blockIdx.y * gridDim.x + blockIdx.x;
    const int xcd  = orig % NXCD;
    const int q    = nwg / NXCD;
    const int rr   = nwg % NXCD;
    const int wgid = (xcd < rr ? xcd * (q + 1) : rr * (q + 1) + (xcd - rr) * q)
                   + orig / NXCD;
    const int bn0  = (wgid % gridDim.x) * BN;
    const int bm0  = (wgid / gridDim.x) * BM;

    const int lrow = lane & 15;
    const int kgrp = lane >> 4;

    // ---- staging: per-thread pre-swizzled source column, linear LDS dest ----
    const int s_colb  = ((tid & 7) * 16) ^ (((tid >> 3) & 7) << 4);
    const int s_row   = tid >> 3;          // 0..63
    const int lds_off = tid * 16;

    const long Kb   = (long)K * 2;         // row stride in bytes
    const long r64  = 64 * Kb;
    const long r128 = 128 * Kb;
    const char* gA0 = (const char*)A  + (long)(bm0 + s_row) * Kb + s_colb;
    const char* gB0 = (const char*)Bm + (long)(bn0 + s_row) * Kb + s_colb;

    auto stageH = [&](int buf, int h, long kb) {
        char* ldst = lds + buf * 65536
                   + (h < 2 ? h * 16384 : 32768 + (h - 2) * 16384) + lds_off;
        const char* g = (h < 2 ? gA0 + h * r128 : gB0 + (h - 2) * r128) + kb;
        __builtin_amdgcn_global_load_lds(AS1(g),       AS3(ldst),        16, 0, 0);
        __builtin_amdgcn_global_load_lds(AS1(g + r64), AS3(ldst + 8192), 16, 0, 0);
    };

    // ---- ds_read addressing (swizzled column), per-buffer address registers ----
    const int swzk  = (lrow & 7) << 4;
    const int colK0 = (kgrp * 16) ^ swzk;            // kk=0
    const int colK1 = (kgrp * 16 + 64) ^ swzk;       // kk=1
    const uint32_t ldsbase = (uint32_t)(uintptr_t)AS3(lds);
    const uint32_t aA00 = ldsbase + (wr * 128 + lrow) * 128 + colK0;
    const uint32_t aA01 = ldsbase + (wr * 128 + lrow) * 128 + colK1;
    const uint32_t aB00 = ldsbase + 32768 + (wc * 64 + lrow) * 128 + colK0;
    const uint32_t aB01 = ldsbase + 32768 + (wc * 64 + lrow) * 128 + colK1;
    const uint32_t aA10 = aA00 + 65536, aA11 = aA01 + 65536;
    const uint32_t aB10 = aB00 + 65536, aB11 = aB01 + 65536;

    facc acc[8][4];
    #pragma unroll
    for (int m = 0; m < 8; ++m)
        #pragma unroll
        for (int n = 0; n < 4; ++n)
            acc[m][n] = facc{0.f, 0.f, 0.f, 0.f};

    const int NT = K / BK;   // 16 or 64 (even)

    bfrag aF[4][2];          // A-lo then A-hi (time-shared)
    bfrag bHi[2][2];         // B-hi of current tile
    bfrag bLoE[2][2];        // B-lo, even tiles
    bfrag bLoO[2][2];        // B-lo, odd tiles

    // ---- prologue: stage tile0 (4 halves) + tile1 H0,H1; preload Q0 frags ----
    stageH(0, 0, 0); stageH(0, 1, 0); stageH(0, 2, 0); stageH(0, 3, 0);
    stageH(1, 0, 128); stageH(1, 1, 128);
    asm volatile("s_waitcnt vmcnt(4)" ::: "memory");
    __builtin_amdgcn_s_barrier();
    #pragma unroll
    for (int m = 0; m < 4; ++m) { DSR(aF[m][0], aA00, 0 * 2048 + 0); DSR(aF[m][1], aA01, 0); }
    // (note: per-m offsets below; unrolled explicitly)
    // -- redo with offsets:
    #pragma unroll
    for (int m = 0; m < 4; ++m) { DSR(aF[m][0], aA00, m * 2048); DSR(aF[m][1], aA01, m * 2048); }
    #pragma unroll
    for (int n = 0; n < 2; ++n) { DSR(bLoE[n][0], aB00, n * 2048); DSR(bLoE[n][1], aB01, n * 2048); }

    auto ktile = [&](int t, int curbuf,
                     uint32_t A0c, uint32_t A1c, uint32_t B0c, uint32_t B1c,
                     uint32_t A0n, uint32_t A1n, uint32_t B0n, uint32_t B1n,
                     bfrag (&bLoC)[2][2], bfrag (&bLoN)[2][2]) {
        const long k1b = (long)(t + 1) * 128;
        const long k2b = (long)(t + 2) * 128;
        const int  nb  = curbuf ^ 1;

        // ---- P0: stage H2(t+1); Q0 = Alo x Blo; post-read B-hi(t) ----
        if (t + 1 < NT) stageH(nb, 2, k1b);
        __builtin_amdgcn_s_barrier();
        asm volatile("s_waitcnt lgkmcnt(0)" ::: "memory");
        __builtin_amdgcn_sched_barrier(0);
        __builtin_amdgcn_s_setprio(1);
        #pragma unroll
        for (int m = 0; m < 4; ++m)
            #pragma unroll
            for (int n = 0; n < 2; ++n) {
                acc[m][n] = MFMA_BF16(aF[m][0], bLoC[n][0], acc[m][n], 0, 0, 0);
                acc[m][n] = MFMA_BF16(aF[m][1], bLoC[n][1], acc[m][n], 0, 0, 0);
            }
        __builtin_amdgcn_s_setprio(0);
        #pragma unroll
        for (int n = 0; n < 2; ++n) {
            DSR(bHi[n][0], B0c, (2 + n) * 2048);
            DSR(bHi[n][1], B1c, (2 + n) * 2048);
        }
        __builtin_amdgcn_s_barrier();

        // ---- P1: stage H3(t+1); Q1 = Alo x Bhi; post-read A-hi(t) -> aF ----
        if (t + 1 < NT) stageH(nb, 3, k1b);
        __builtin_amdgcn_s_barrier();
        asm volatile("s_waitcnt lgkmcnt(0)" ::: "memory");
        __builtin_amdgcn_sched_barrier(0);
        __builtin_amdgcn_s_setprio(1);
        #pragma unroll
        for (int m = 0; m < 4; ++m)
            #pragma unroll
            for (int n = 0; n < 2; ++n) {
                acc[m][n + 2] = MFMA_BF16(aF[m][0], bHi[n][0], acc[m][n + 2], 0, 0, 0);
                acc[m][n + 2] = MFMA_BF16(aF[m][1], bHi[n][1], acc[m][n + 2], 0, 0, 0);
            }
        __builtin_amdgcn_s_setprio(0);
        #pragma unroll
        for (int m = 0; m < 4; ++m) {
            DSR(aF[m][0], A0c, (4 + m) * 2048);
            DSR(aF[m][1], A1c, (4 + m) * 2048);
        }
        __builtin_amdgcn_s_barrier();

        // ---- P2: stage H0(t+2) -> cur A-lo (fully read); Q2 = Ahi x Bhi ----
        if (t + 2 < NT) stageH(curbuf, 0, k2b);
        __builtin_amdgcn_s_barrier();
        asm volatile("s_waitcnt lgkmcnt(0)" ::: "memory");
        __builtin_amdgcn_sched_barrier(0);
        __builtin_amdgcn_s_setprio(1);
        #pragma unroll
        for (int m = 0; m < 4; ++m)
            #pragma unroll
            for (int n = 0; n < 2; ++n) {
                acc[m + 4][n + 2] = MFMA_BF16(aF[m][0], bHi[n][0], acc[m + 4][n + 2], 0, 0, 0);
                acc[m + 4][n + 2] = MFMA_BF16(aF[m][1], bHi[n][1], acc[m + 4][n + 2], 0, 0, 0);
            }
        __builtin_amdgcn_s_setprio(0);
        __builtin_amdgcn_s_barrier();

        // ---- P3: stage H1(t+2) -> cur A-hi; vmcnt(4) (tile t+1 resident);
        //          Q3 = Ahi x Blo; post-read next tile's A-lo/B-lo ----
        if (t + 2 < NT) {
            stageH(curbuf, 1, k2b);
            asm volatile("s_waitcnt vmcnt(4)" ::: "memory");
        } else if (t + 1 < NT) {
            asm volatile("s_waitcnt vmcnt(0)" ::: "memory");
        }
        __builtin_amdgcn_s_barrier();
        asm volatile("s_waitcnt lgkmcnt(0)" ::: "memory");
        __builtin_amdgcn_sched_barrier(0);
        __builtin_amdgcn_s_setprio(1);
        #pragma unroll
        for (int m = 0; m < 4; ++m)
            #pragma unroll
            for (int n = 0; n < 2; ++n) {
                acc[m + 4][n] = MFMA_BF16(aF[m][0], bLoC[n][0], acc[m + 4][n], 0, 0, 0);
                acc[m + 4][n] = MFMA_BF16(aF[m][1], bLoC[n][1], acc[m + 4][n], 0, 0, 0);
            }
        __builtin_amdgcn_s_setprio(0);
        if (t + 1 < NT) {
            #pragma unroll
            for (int m = 0; m < 4; ++m) {
                DSR(aF[m][0], A0n, m * 2048);
                DSR(aF[m][1], A1n, m * 2048);
            }
            #pragma unroll
            for (int n = 0; n < 2; ++n) {
                DSR(bLoN[n][0], B0n, n * 2048);
                DSR(bLoN[n][1], B1n, n * 2048);
            }
        }
        __builtin_amdgcn_s_barrier();
    };

    for (int t = 0; t < NT; t += 2) {
        ktile(t,     0, aA00, aA01, aB00, aB01, aA10, aA11, aB10, aB11, bLoE, bLoO);
        ktile(t + 1, 1, aA10, aA11, aB10, aB11, aA00, aA01, aB00, aB01, bLoO, bLoE);
    }

    // ---------------- epilogue ----------------
    if constexpr (EPI == 2) {
        float* Cf = reinterpret_cast<float*>(Cout);
        float b2c[4][R_];
        #pragma unroll
        for (int n = 0; n < 4; ++n) {
            const int col = bn0 + wc * 64 + n * 16 + lrow;
            #pragma unroll
            for (int r = 0; r < R_; ++r) b2c[n][r] = b2v[r * N + col];
        }
        #pragma unroll
        for (int m = 0; m < 8; ++m) {
            #pragma unroll
            for (int j = 0; j < 4; ++j) {
                const int row = bm0 + wr * 128 + m * 16 + kgrp * 4 + j;
                const float* g = gate + (long)(gate_row0 + row) * R_;
                float gv[R_];
                #pragma unroll
                for (int r = 0; r < R_; ++r) gv[r] = g[r];
                #pragma unroll
                for (int n = 0; n < 4; ++n) {
                    const int col = bn0 + wc * 64 + n * 16 + lrow;
                    float sv = acc[m][n][j];
                    #pragma unroll
                    for (int r = 0; r < R_; ++r) sv += gv[r] * b2c[n][r];
                    Cf[(long)row * N + col] = sv;
                }
            }
        }
    } else {
        bf16* Cb = reinterpret_cast<bf16*>(Cout);
        float bcol[4];
        #pragma unroll
        for (int n = 0; n < 4; ++n) bcol[n] = bias[bn0 + wc * 64 + n * 16 + lrow];
        #pragma unroll
        for (int m = 0; m < 8; ++m) {
            #pragma unroll
            for (int j = 0; j < 4; ++j) {
                const int row = bm0 + wr * 128 + m * 16 + kgrp * 4 + j;
                float gv[4];
                if constexpr (EPI == 1) {
                    #pragma unroll
                    for (int n = 0; n < 4; ++n) {
                        const int col = bn0 + wc * 64 + n * 16 + lrow;
                        gv[n] = gate[(long)(gate_row0 + row) * R_ + (col >> 9)];
                    }
                }
                #pragma unroll
                for (int n = 0; n < 4; ++n) {
                    const int col = bn0 + wc * 64 + n * 16 + lrow;
                    float v = acc[m][n][j] + bcol[n];
                    if constexpr (EPI == 1) v = fmaxf(v, 0.f) * gv[n];
                    Cb[(long)row * N + col] = __float2bfloat16(v);
                }
            }
        }
    }
}

extern "C" void kernel_launch(void* const* d_in, const int* in_sizes, int n_in,
                              void* d_out, int out_size, void* d_ws, size_t ws_size,
                              hipStream_t stream)
{
    const float* x   = (const float*)d_in[0];
    const float* ipw = (const float*)d_in[1];
    const float* ipb = (const float*)d_in[2];
    const float* opw = (const float*)d_in[3];
    const float* opb = (const float*)d_in[4];
    const float* W1  = (const float*)d_in[5];
    const float* b1  = (const float*)d_in[6];
    const float* W2  = (const float*)d_in[7];
    const float* b2  = (const float*)d_in[8];
    const float* Wg  = (const float*)d_in[9];
    const float* bg  = (const float*)d_in[10];
    float* out = (float*)d_out;

    char* ws = (char*)d_ws;
    size_t off = 0;
    auto alloc = [&](size_t bytes) -> void* {
        void* p = ws + off;
        off += (bytes + 255) & ~(size_t)255;
        return p;
    };

    bf16* xb   = (bf16*)alloc((size_t)B_ * D_ * 2);     // x in bf16
    bf16* vb   = (bf16*)alloc((size_t)B_ * D_ * 2);     // v
    bf16* Wvb  = (bf16*)alloc((size_t)D_ * D_ * 2);
    bf16* Wob  = (bf16*)alloc((size_t)D_ * D_ * 2);
    bf16* W1b  = (bf16*)alloc((size_t)RH_ * D_ * 2);
    bf16* W2b  = (bf16*)alloc((size_t)DOUT_ * RH_ * 2);
    float* gate = (float*)alloc((size_t)B_ * R_ * 4);

    // h' chunk buffer: largest M-chunk that fits the workspace (multiple of 256)
    int mc = B_;
    while (off + (size_t)mc * RH_ * 2 > ws_size && mc > 1024) mc >>= 1;
    bf16* hb = (bf16*)alloc((size_t)mc * RH_ * 2);
    bf16* ab = xb;   // attended reuses xb (xb is dead after G1; gate reads fp32 x)

    // ---- conversions ----
    k_cvt<<<(B_ * D_) / 1024, 256, 0, stream>>>(x, xb, (long)B_ * D_);
    k_cvt<<<(D_ * D_) / 1024, 256, 0, stream>>>(ipw + (size_t)2 * D_ * D_, Wvb, (long)D_ * D_);
    k_cvt<<<(D_ * D_) / 1024, 256, 0, stream>>>(opw, Wob, (long)D_ * D_);
    k_cvt<<<(RH_ * D_) / 1024, 256, 0, stream>>>(W1, W1b, (long)RH_ * D_);
    k_cvt_w2<<<R_ * DOUT_, 128, 0, stream>>>(W2, W2b);

    // ---- gate (reads fp32 x directly) ----
    k_gate<<<B_ / 4, 256, 0, stream>>>(x, Wg, bg, gate);

    // ---- G1: v = x @ Wv^T + bv ----
    k_gemm<0><<<dim3(D_ / BN, B_ / BM), 512, 0, stream>>>(
        xb, Wvb, ipb + 2 * D_, nullptr, nullptr, vb, B_, D_, D_, 0);

    // ---- G2: attended = v @ Wout^T + bout ----
    k_gemm<0><<<dim3(D_ / BN, B_ / BM), 512, 0, stream>>>(
        vb, Wob, opb, nullptr, nullptr, ab, B_, D_, D_, 0);

    // ---- G3 + G4, chunked over M ----
    for (int m0 = 0; m0 < B_; m0 += mc) {
        // h' = relu(att @ W1cat^T + b1) * gate[:, r]
        k_gemm<1><<<dim3(RH_ / BN, mc / BM), 512, 0, stream>>>(
            ab + (size_t)m0 * D_, W1b, b1, gate, nullptr, hb, mc, RH_, D_, m0);
        // out = h' @ W2cat + gate @ b2
        k_gemm<2><<<dim3(DOUT_ / BN, mc / BM), 512, 0, stream>>>(
            hb, W2b, nullptr, gate, b2, out + (size_t)m0 * DOUT_, mc, DOUT_, RH_, m0);
    }
}

// Round 6
// 377.318 us; speedup vs baseline: 1.0288x; 1.0288x over previous
//
#include <hip/hip_runtime.h>
#include <hip/hip_bf16.h>
#include <cstdint>

typedef __hip_bfloat16 bf16;
typedef __attribute__((ext_vector_type(8))) short bfrag;   // 8 bf16 (4 VGPRs)
typedef __attribute__((ext_vector_type(4))) float facc;    // 4 fp32 acc

#define B_    16384
#define D_    1024
#define DOUT_ 1024
#define R_    8
#define DH_   512
#define RH_   4096

#define BM 256
#define BN 256
#define BK 64

#define NXCD 8

#define AS1(p) ((const __attribute__((address_space(1))) void*)(p))
#define AS3(p) ((__attribute__((address_space(3))) void*)(p))

// inline-asm ds_read_b128 (fixed issue order; lgkm counted against these only).
#define DSR(dst, addr, off) \
    asm volatile("ds_read_b128 %0, %1 offset:%c2" : "=v"(dst) : "v"(addr), "i"(off))
#define LGKM(n) do { asm volatile("s_waitcnt lgkmcnt(" #n ")" ::: "memory"); \
                     __builtin_amdgcn_sched_barrier(0); } while (0)

static __device__ __forceinline__ uint32_t pack2bf(float a, float b) {
    unsigned short ua = __builtin_bit_cast(unsigned short, __float2bfloat16(a));
    unsigned short ub = __builtin_bit_cast(unsigned short, __float2bfloat16(b));
    return (uint32_t)ua | ((uint32_t)ub << 16);
}

// ---------------- fp32 -> bf16 conversion (vectorized) ----------------
__global__ void k_cvt(const float* __restrict__ in, bf16* __restrict__ out, long n)
{
    long i = ((long)blockIdx.x * blockDim.x + threadIdx.x) * 4;
    if (i >= n) return;
    float4 v = *reinterpret_cast<const float4*>(in + i);
    uint2 o;
    o.x = pack2bf(v.x, v.y);
    o.y = pack2bf(v.z, v.w);
    *reinterpret_cast<uint2*>(out + i) = o;
}

// ---- W2 (R,DOUT,DH) -> B4 (DOUT, R*DH) with B4[o][r*DH+h] = W2[r][o][h] ----
__global__ void k_cvt_w2(const float* __restrict__ W2, bf16* __restrict__ out)
{
    int b = blockIdx.x;            // 0 .. R_*DOUT_-1
    int r = b >> 10;               // DOUT_ = 1024
    int o = b & 1023;
    const float4* src = reinterpret_cast<const float4*>(W2 + ((long)r * DOUT_ + o) * DH_);
    bf16* dst = out + (long)o * RH_ + r * DH_;
    int t = threadIdx.x;           // 0..127, covers 512 floats
    float4 v = src[t];
    uint2 p;
    p.x = pack2bf(v.x, v.y);
    p.y = pack2bf(v.z, v.w);
    *reinterpret_cast<uint2*>(dst + t * 4) = p;
}

// ---------------- gate = softmax(x @ Wg.T + bg) ----------------
__global__ __launch_bounds__(256) void k_gate(const float* __restrict__ x,
                                              const float* __restrict__ Wg,
                                              const float* __restrict__ bg,
                                              float* __restrict__ gate)
{
    __shared__ float sWg[R_ * D_];
    __shared__ float sbg[R_];
    for (int i = threadIdx.x; i < R_ * D_ / 4; i += 256)
        reinterpret_cast<float4*>(sWg)[i] = reinterpret_cast<const float4*>(Wg)[i];
    if (threadIdx.x < R_) sbg[threadIdx.x] = bg[threadIdx.x];
    __syncthreads();

    const int lane = threadIdx.x & 63;
    const int wave = threadIdx.x >> 6;
    const int row  = blockIdx.x * 4 + wave;     // grid = B_/4

    const float4* xr = reinterpret_cast<const float4*>(x + (long)row * D_);
    float s[R_] = {};
    #pragma unroll
    for (int c = 0; c < 4; ++c) {
        float4 xv = xr[lane + c * 64];
        #pragma unroll
        for (int r = 0; r < R_; ++r) {
            float4 wv = reinterpret_cast<const float4*>(sWg + r * D_)[lane + c * 64];
            s[r] += xv.x * wv.x + xv.y * wv.y + xv.z * wv.z + xv.w * wv.w;
        }
    }
    #pragma unroll
    for (int r = 0; r < R_; ++r) {
        float v = s[r];
        #pragma unroll
        for (int off = 32; off > 0; off >>= 1) v += __shfl_xor(v, off);
        s[r] = v + sbg[r];
    }
    float m = s[0];
    #pragma unroll
    for (int r = 1; r < R_; ++r) m = fmaxf(m, s[r]);
    float den = 0.f;
    #pragma unroll
    for (int r = 0; r < R_; ++r) { s[r] = __expf(s[r] - m); den += s[r]; }
    float inv = 1.f / den;
    if (lane < R_) gate[(long)row * R_ + lane] = s[lane] * inv;
}

// ======== 256x256 8-phase bf16 MFMA GEMM (read-ahead + counted lgkm) ========
// EPI 0: C(bf16) = dot + bias[col]
// EPI 1: C(bf16) = relu(dot + bias[col]) * gate[row][col>>9]
// EPI 2: C(f32)  = dot + sum_r gate[row][r]*b2[r][col]
//
// Quadrants: Q0(Alo,Blo) Q1(Alo,Bhi) Q2(Ahi,Bhi) Q3(Ahi,Blo).
// Reads for phase p issued at END of phase p-1 in FIXED order; phase p's MFMA
// cluster uses counted lgkmcnt so MFMAs start as fragments land and the LDS
// queue drains DURING the cluster. Staging 1 half-tile/phase; vmcnt(4)/tile.
#define MFMA_BF16 __builtin_amdgcn_mfma_f32_16x16x32_bf16

template <int EPI>
__global__ __launch_bounds__(512, 2)
void k_gemm(const bf16* __restrict__ A, const bf16* __restrict__ Bm,
            const float* __restrict__ bias, const float* __restrict__ gate,
            const float* __restrict__ b2v, void* __restrict__ Cout,
            int M, int N, int K, int gate_row0)
{
    __shared__ char lds[131072];

    const int tid  = threadIdx.x;
    const int lane = tid & 63;
    const int wave = tid >> 6;
    const int wr   = wave >> 2;       // 0..1
    const int wc   = wave & 3;        // 0..3

    // ---- XCD-aware bijective chunked swizzle (m204) ----
    const int nwg  = gridDim.x * gridDim.y;
    const int orig = blockIdx.y * gridDim.x + blockIdx.x;
    const int xcd  = orig % NXCD;
    const int q    = nwg / NXCD;
    const int rr   = nwg % NXCD;
    const int wgid = (xcd < rr ? xcd * (q + 1) : rr * (q + 1) + (xcd - rr) * q)
                   + orig / NXCD;
    const int bn0  = (wgid % gridDim.x) * BN;
    const int bm0  = (wgid / gridDim.x) * BM;

    const int lrow = lane & 15;
    const int kgrp = lane >> 4;

    // ---- staging: per-thread pre-swizzled source column, linear LDS dest ----
    const int s_colb  = ((tid & 7) * 16) ^ (((tid >> 3) & 7) << 4);
    const int s_row   = tid >> 3;          // 0..63
    const int lds_off = tid * 16;

    const long Kb   = (long)K * 2;         // row stride in bytes
    const long r64  = 64 * Kb;
    const long r128 = 128 * Kb;
    const char* gA0 = (const char*)A  + (long)(bm0 + s_row) * Kb + s_colb;
    const char* gB0 = (const char*)Bm + (long)(bn0 + s_row) * Kb + s_colb;

    auto stageH = [&](int buf, int h, long kb) {
        char* ldst = lds + buf * 65536
                   + (h < 2 ? h * 16384 : 32768 + (h - 2) * 16384) + lds_off;
        const char* g = (h < 2 ? gA0 + h * r128 : gB0 + (h - 2) * r128) + kb;
        __builtin_amdgcn_global_load_lds(AS1(g),       AS3(ldst),        16, 0, 0);
        __builtin_amdgcn_global_load_lds(AS1(g + r64), AS3(ldst + 8192), 16, 0, 0);
    };

    // ---- ds_read addressing (swizzled column), per-buffer address registers ----
    const int swzk  = (lrow & 7) << 4;
    const int colK0 = (kgrp * 16) ^ swzk;            // kk=0
    const int colK1 = (kgrp * 16 + 64) ^ swzk;       // kk=1
    const uint32_t ldsbase = (uint32_t)(uintptr_t)AS3(lds);
    const uint32_t aA00 = ldsbase + (wr * 128 + lrow) * 128 + colK0;
    const uint32_t aA01 = ldsbase + (wr * 128 + lrow) * 128 + colK1;
    const uint32_t aB00 = ldsbase + 32768 + (wc * 64 + lrow) * 128 + colK0;
    const uint32_t aB01 = ldsbase + 32768 + (wc * 64 + lrow) * 128 + colK1;
    const uint32_t aA10 = aA00 + 65536, aA11 = aA01 + 65536;
    const uint32_t aB10 = aB00 + 65536, aB11 = aB01 + 65536;

    facc acc[8][4];
    #pragma unroll
    for (int m = 0; m < 8; ++m)
        #pragma unroll
        for (int n = 0; n < 4; ++n)
            acc[m][n] = facc{0.f, 0.f, 0.f, 0.f};

    const int NT = K / BK;   // 16 or 64 (even)

    bfrag aF[4][2];          // A-lo then A-hi (time-shared)
    bfrag bHi[2][2];         // B-hi of current tile
    bfrag bLoE[2][2];        // B-lo, even tiles
    bfrag bLoO[2][2];        // B-lo, odd tiles

    // canonical Q0 read order: bLo[0][0], bLo[0][1], bLo[1][0], bLo[1][1],
    // then aF[m][0], aF[m][1] for m=0..3  (12 reads)
    auto rdQ0 = [&](bfrag (&bLo)[2][2], uint32_t A0, uint32_t A1,
                    uint32_t B0, uint32_t B1) {
        DSR(bLo[0][0], B0, 0);    DSR(bLo[0][1], B1, 0);
        DSR(bLo[1][0], B0, 2048); DSR(bLo[1][1], B1, 2048);
        #pragma unroll
        for (int m = 0; m < 4; ++m) {
            DSR(aF[m][0], A0, m * 2048);
            DSR(aF[m][1], A1, m * 2048);
        }
    };

    // ---- prologue: stage tile0 (H0-H3) + tile1 (H0,H1); preload Q0 frags ----
    stageH(0, 0, 0); stageH(0, 1, 0); stageH(0, 2, 0); stageH(0, 3, 0);
    stageH(1, 0, 128); stageH(1, 1, 128);
    asm volatile("s_waitcnt vmcnt(4)" ::: "memory");
    __builtin_amdgcn_s_barrier();
    rdQ0(bLoE, aA00, aA01, aB00, aB01);

    auto ktile = [&](int t, int curbuf,
                     uint32_t A0c, uint32_t A1c, uint32_t B0c, uint32_t B1c,
                     uint32_t A0n, uint32_t A1n, uint32_t B0n, uint32_t B1n,
                     bfrag (&bLoC)[2][2], bfrag (&bLoN)[2][2]) {
        const long k1b = (long)(t + 1) * 128;
        const long k2b = (long)(t + 2) * 128;
        const int  nb  = curbuf ^ 1;

        // ===== P0: Q0 = Alo x Blo  (12 outstanding: bLo4 + aLo8) =====
        if (t + 1 < NT) stageH(nb, 2, k1b);
        __builtin_amdgcn_s_barrier();
        __builtin_amdgcn_s_setprio(1);
        LGKM(6);
        acc[0][0] = MFMA_BF16(aF[0][0], bLoC[0][0], acc[0][0], 0, 0, 0);
        acc[0][0] = MFMA_BF16(aF[0][1], bLoC[0][1], acc[0][0], 0, 0, 0);
        acc[0][1] = MFMA_BF16(aF[0][0], bLoC[1][0], acc[0][1], 0, 0, 0);
        acc[0][1] = MFMA_BF16(aF[0][1], bLoC[1][1], acc[0][1], 0, 0, 0);
        LGKM(4);
        acc[1][0] = MFMA_BF16(aF[1][0], bLoC[0][0], acc[1][0], 0, 0, 0);
        acc[1][0] = MFMA_BF16(aF[1][1], bLoC[0][1], acc[1][0], 0, 0, 0);
        acc[1][1] = MFMA_BF16(aF[1][0], bLoC[1][0], acc[1][1], 0, 0, 0);
        acc[1][1] = MFMA_BF16(aF[1][1], bLoC[1][1], acc[1][1], 0, 0, 0);
        LGKM(2);
        acc[2][0] = MFMA_BF16(aF[2][0], bLoC[0][0], acc[2][0], 0, 0, 0);
        acc[2][0] = MFMA_BF16(aF[2][1], bLoC[0][1], acc[2][0], 0, 0, 0);
        acc[2][1] = MFMA_BF16(aF[2][0], bLoC[1][0], acc[2][1], 0, 0, 0);
        acc[2][1] = MFMA_BF16(aF[2][1], bLoC[1][1], acc[2][1], 0, 0, 0);
        LGKM(0);
        acc[3][0] = MFMA_BF16(aF[3][0], bLoC[0][0], acc[3][0], 0, 0, 0);
        acc[3][0] = MFMA_BF16(aF[3][1], bLoC[0][1], acc[3][0], 0, 0, 0);
        acc[3][1] = MFMA_BF16(aF[3][0], bLoC[1][0], acc[3][1], 0, 0, 0);
        acc[3][1] = MFMA_BF16(aF[3][1], bLoC[1][1], acc[3][1], 0, 0, 0);
        __builtin_amdgcn_s_setprio(0);
        DSR(bHi[0][0], B0c, 2 * 2048); DSR(bHi[0][1], B1c, 2 * 2048);
        DSR(bHi[1][0], B0c, 3 * 2048); DSR(bHi[1][1], B1c, 3 * 2048);
        __builtin_amdgcn_s_barrier();

        // ===== P1: Q1 = Alo x Bhi  (4 outstanding: bHi) =====
        if (t + 1 < NT) stageH(nb, 3, k1b);
        __builtin_amdgcn_s_barrier();
        __builtin_amdgcn_s_setprio(1);
        LGKM(2);
        #pragma unroll
        for (int m = 0; m < 4; ++m) {
            acc[m][2] = MFMA_BF16(aF[m][0], bHi[0][0], acc[m][2], 0, 0, 0);
            acc[m][2] = MFMA_BF16(aF[m][1], bHi[0][1], acc[m][2], 0, 0, 0);
        }
        LGKM(0);
        #pragma unroll
        for (int m = 0; m < 4; ++m) {
            acc[m][3] = MFMA_BF16(aF[m][0], bHi[1][0], acc[m][3], 0, 0, 0);
            acc[m][3] = MFMA_BF16(aF[m][1], bHi[1][1], acc[m][3], 0, 0, 0);
        }
        __builtin_amdgcn_s_setprio(0);
        #pragma unroll
        for (int m = 0; m < 4; ++m) {
            DSR(aF[m][0], A0c, (4 + m) * 2048);
            DSR(aF[m][1], A1c, (4 + m) * 2048);
        }
        __builtin_amdgcn_s_barrier();

        // ===== P2: Q2 = Ahi x Bhi  (8 outstanding: aHi) =====
        if (t + 2 < NT) stageH(curbuf, 0, k2b);
        __builtin_amdgcn_s_barrier();
        __builtin_amdgcn_s_setprio(1);
        LGKM(6);
        acc[4][2] = MFMA_BF16(aF[0][0], bHi[0][0], acc[4][2], 0, 0, 0);
        acc[4][2] = MFMA_BF16(aF[0][1], bHi[0][1], acc[4][2], 0, 0, 0);
        acc[4][3] = MFMA_BF16(aF[0][0], bHi[1][0], acc[4][3], 0, 0, 0);
        acc[4][3] = MFMA_BF16(aF[0][1], bHi[1][1], acc[4][3], 0, 0, 0);
        LGKM(4);
        acc[5][2] = MFMA_BF16(aF[1][0], bHi[0][0], acc[5][2], 0, 0, 0);
        acc[5][2] = MFMA_BF16(aF[1][1], bHi[0][1], acc[5][2], 0, 0, 0);
        acc[5][3] = MFMA_BF16(aF[1][0], bHi[1][0], acc[5][3], 0, 0, 0);
        acc[5][3] = MFMA_BF16(aF[1][1], bHi[1][1], acc[5][3], 0, 0, 0);
        LGKM(2);
        acc[6][2] = MFMA_BF16(aF[2][0], bHi[0][0], acc[6][2], 0, 0, 0);
        acc[6][2] = MFMA_BF16(aF[2][1], bHi[0][1], acc[6][2], 0, 0, 0);
        acc[6][3] = MFMA_BF16(aF[2][0], bHi[1][0], acc[6][3], 0, 0, 0);
        acc[6][3] = MFMA_BF16(aF[2][1], bHi[1][1], acc[6][3], 0, 0, 0);
        LGKM(0);
        acc[7][2] = MFMA_BF16(aF[3][0], bHi[0][0], acc[7][2], 0, 0, 0);
        acc[7][2] = MFMA_BF16(aF[3][1], bHi[0][1], acc[7][2], 0, 0, 0);
        acc[7][3] = MFMA_BF16(aF[3][0], bHi[1][0], acc[7][3], 0, 0, 0);
        acc[7][3] = MFMA_BF16(aF[3][1], bHi[1][1], acc[7][3], 0, 0, 0);
        __builtin_amdgcn_s_setprio(0);
        __builtin_amdgcn_s_barrier();

        // ===== P3: Q3 = Ahi x Blo  (0 outstanding: no lgkm waits) =====
        if (t + 2 < NT) {
            stageH(curbuf, 1, k2b);
            asm volatile("s_waitcnt vmcnt(4)" ::: "memory");
        } else if (t + 1 < NT) {
            asm volatile("s_waitcnt vmcnt(0)" ::: "memory");
        }
        __builtin_amdgcn_s_barrier();
        __builtin_amdgcn_s_setprio(1);
        #pragma unroll
        for (int m = 0; m < 4; ++m) {
            acc[4 + m][0] = MFMA_BF16(aF[m][0], bLoC[0][0], acc[4 + m][0], 0, 0, 0);
            acc[4 + m][0] = MFMA_BF16(aF[m][1], bLoC[0][1], acc[4 + m][0], 0, 0, 0);
            acc[4 + m][1] = MFMA_BF16(aF[m][0], bLoC[1][0], acc[4 + m][1], 0, 0, 0);
            acc[4 + m][1] = MFMA_BF16(aF[m][1], bLoC[1][1], acc[4 + m][1], 0, 0, 0);
        }
        __builtin_amdgcn_s_setprio(0);
        if (t + 1 < NT) rdQ0(bLoN, A0n, A1n, B0n, B1n);
        __builtin_amdgcn_s_barrier();
    };

    for (int t = 0; t < NT; t += 2) {
        ktile(t,     0, aA00, aA01, aB00, aB01, aA10, aA11, aB10, aB11, bLoE, bLoO);
        ktile(t + 1, 1, aA10, aA11, aB10, aB11, aA00, aA01, aB00, aB01, bLoO, bLoE);
    }

    // ---------------- epilogue ----------------
    if constexpr (EPI == 2) {
        float* Cf = reinterpret_cast<float*>(Cout);
        float b2c[4][R_];
        #pragma unroll
        for (int n = 0; n < 4; ++n) {
            const int col = bn0 + wc * 64 + n * 16 + lrow;
            #pragma unroll
            for (int r = 0; r < R_; ++r) b2c[n][r] = b2v[r * N + col];
        }
        #pragma unroll
        for (int m = 0; m < 8; ++m) {
            #pragma unroll
            for (int j = 0; j < 4; ++j) {
                const int row = bm0 + wr * 128 + m * 16 + kgrp * 4 + j;
                const float* g = gate + (long)(gate_row0 + row) * R_;
                float gv[R_];
                #pragma unroll
                for (int r = 0; r < R_; ++r) gv[r] = g[r];
                #pragma unroll
                for (int n = 0; n < 4; ++n) {
                    const int col = bn0 + wc * 64 + n * 16 + lrow;
                    float sv = acc[m][n][j];
                    #pragma unroll
                    for (int r = 0; r < R_; ++r) sv += gv[r] * b2c[n][r];
                    Cf[(long)row * N + col] = sv;
                }
            }
        }
    } else {
        bf16* Cb = reinterpret_cast<bf16*>(Cout);
        float bcol[4];
        #pragma unroll
        for (int n = 0; n < 4; ++n) bcol[n] = bias[bn0 + wc * 64 + n * 16 + lrow];
        #pragma unroll
        for (int m = 0; m < 8; ++m) {
            #pragma unroll
            for (int j = 0; j < 4; ++j) {
                const int row = bm0 + wr * 128 + m * 16 + kgrp * 4 + j;
                float gv[4];
                if constexpr (EPI == 1) {
                    #pragma unroll
                    for (int n = 0; n < 4; ++n) {
                        const int col = bn0 + wc * 64 + n * 16 + lrow;
                        gv[n] = gate[(long)(gate_row0 + row) * R_ + (col >> 9)];
                    }
                }
                #pragma unroll
                for (int n = 0; n < 4; ++n) {
                    const int col = bn0 + wc * 64 + n * 16 + lrow;
                    float v = acc[m][n][j] + bcol[n];
                    if constexpr (EPI == 1) v = fmaxf(v, 0.f) * gv[n];
                    Cb[(long)row * N + col] = __float2bfloat16(v);
                }
            }
        }
    }
}

extern "C" void kernel_launch(void* const* d_in, const int* in_sizes, int n_in,
                              void* d_out, int out_size, void* d_ws, size_t ws_size,
                              hipStream_t stream)
{
    const float* x   = (const float*)d_in[0];
    const float* ipw = (const float*)d_in[1];
    const float* ipb = (const float*)d_in[2];
    const float* opw = (const float*)d_in[3];
    const float* opb = (const float*)d_in[4];
    const float* W1  = (const float*)d_in[5];
    const float* b1  = (const float*)d_in[6];
    const float* W2  = (const float*)d_in[7];
    const float* b2  = (const float*)d_in[8];
    const float* Wg  = (const float*)d_in[9];
    const float* bg  = (const float*)d_in[10];
    float* out = (float*)d_out;

    char* ws = (char*)d_ws;
    size_t off = 0;
    auto alloc = [&](size_t bytes) -> void* {
        void* p = ws + off;
        off += (bytes + 255) & ~(size_t)255;
        return p;
    };

    bf16* xb   = (bf16*)alloc((size_t)B_ * D_ * 2);     // x in bf16
    bf16* vb   = (bf16*)alloc((size_t)B_ * D_ * 2);     // v
    bf16* Wvb  = (bf16*)alloc((size_t)D_ * D_ * 2);
    bf16* Wob  = (bf16*)alloc((size_t)D_ * D_ * 2);
    bf16* W1b  = (bf16*)alloc((size_t)RH_ * D_ * 2);
    bf16* W2b  = (bf16*)alloc((size_t)DOUT_ * RH_ * 2);
    float* gate = (float*)alloc((size_t)B_ * R_ * 4);

    // h' chunk buffer: largest M-chunk that fits the workspace (multiple of 256)
    int mc = B_;
    while (off + (size_t)mc * RH_ * 2 > ws_size && mc > 1024) mc >>= 1;
    bf16* hb = (bf16*)alloc((size_t)mc * RH_ * 2);
    bf16* ab = xb;   // attended reuses xb (xb is dead after G1; gate reads fp32 x)

    // ---- conversions ----
    k_cvt<<<(B_ * D_) / 1024, 256, 0, stream>>>(x, xb, (long)B_ * D_);
    k_cvt<<<(D_ * D_) / 1024, 256, 0, stream>>>(ipw + (size_t)2 * D_ * D_, Wvb, (long)D_ * D_);
    k_cvt<<<(D_ * D_) / 1024, 256, 0, stream>>>(opw, Wob, (long)D_ * D_);
    k_cvt<<<(RH_ * D_) / 1024, 256, 0, stream>>>(W1, W1b, (long)RH_ * D_);
    k_cvt_w2<<<R_ * DOUT_, 128, 0, stream>>>(W2, W2b);

    // ---- gate (reads fp32 x directly) ----
    k_gate<<<B_ / 4, 256, 0, stream>>>(x, Wg, bg, gate);

    // ---- G1: v = x @ Wv^T + bv ----
    k_gemm<0><<<dim3(D_ / BN, B_ / BM), 512, 0, stream>>>(
        xb, Wvb, ipb + 2 * D_, nullptr, nullptr, vb, B_, D_, D_, 0);

    // ---- G2: attended = v @ Wout^T + bout ----
    k_gemm<0><<<dim3(D_ / BN, B_ / BM), 512, 0, stream>>>(
        vb, Wob, opb, nullptr, nullptr, ab, B_, D_, D_, 0);

    // ---- G3 + G4, chunked over M ----
    for (int m0 = 0; m0 < B_; m0 += mc) {
        // h' = relu(att @ W1cat^T + b1) * gate[:, r]
        k_gemm<1><<<dim3(RH_ / BN, mc / BM), 512, 0, stream>>>(
            ab + (size_t)m0 * D_, W1b, b1, gate, nullptr, hb, mc, RH_, D_, m0);
        // out = h' @ W2cat + gate @ b2
        k_gemm<2><<<dim3(DOUT_ / BN, mc / BM), 512, 0, stream>>>(
            hb, W2b, nullptr, gate, b2, out + (size_t)m0 * DOUT_, mc, DOUT_, RH_, m0);
    }
}